// Round 2
// baseline (238.110 us; speedup 1.0000x reference)
//
#include <hip/hip_runtime.h>
#include <stdint.h>

#define NSUP   50000
#define NSUPP  50176      // padded to multiple of 256
#define NQRY   2048
#define KD     512
#define BK     32
#define NKT    16         // KD / BK

typedef __attribute__((ext_vector_type(8))) short bf16x8;
typedef __attribute__((ext_vector_type(4))) float f32x4;

__device__ __forceinline__ unsigned short f2bf(float f) {
  unsigned int u = __float_as_uint(f);
  u += 0x7FFFu + ((u >> 16) & 1u);   // round-to-nearest-even
  return (unsigned short)(u >> 16);
}

// ---- prep: fused norm + normalize + f32->bf16 (+ zero pad rows) ----
// One wave per row; rows [0,NSUPP) = support (pad rows zeroed),
// rows [NSUPP, NSUPP+NQRY) = query. Stores row/||row|| in bf16.
__global__ __launch_bounds__(256) void prep_kernel(
    const float* __restrict__ sup, const float* __restrict__ qry,
    unsigned short* __restrict__ s_bf, unsigned short* __restrict__ q_bf) {
  const int row  = blockIdx.x * 4 + (threadIdx.x >> 6);
  const int lane = threadIdx.x & 63;

  const float* src = nullptr;
  unsigned short* dst;
  if (row < NSUPP) {
    dst = s_bf + (size_t)row * KD;
    if (row < NSUP) src = sup + (size_t)row * KD;
  } else {
    const int r = row - NSUPP;
    dst = q_bf + (size_t)r * KD;
    src = qry + (size_t)r * KD;
  }

  if (src == nullptr) {           // zero pad row
    bf16x8 z = {};
    *(bf16x8*)(dst + lane * 8) = z;
    return;
  }

  const float4 v0 = ((const float4*)src)[lane * 2 + 0];
  const float4 v1 = ((const float4*)src)[lane * 2 + 1];
  float ss = v0.x*v0.x + v0.y*v0.y + v0.z*v0.z + v0.w*v0.w
           + v1.x*v1.x + v1.y*v1.y + v1.z*v1.z + v1.w*v1.w;
  #pragma unroll
  for (int off = 32; off > 0; off >>= 1) ss += __shfl_xor(ss, off);
  const float inv = rsqrtf(fmaxf(ss, 1e-30f));

  bf16x8 o;
  o[0]=(short)f2bf(v0.x*inv); o[1]=(short)f2bf(v0.y*inv);
  o[2]=(short)f2bf(v0.z*inv); o[3]=(short)f2bf(v0.w*inv);
  o[4]=(short)f2bf(v1.x*inv); o[5]=(short)f2bf(v1.y*inv);
  o[6]=(short)f2bf(v1.z*inv); o[7]=(short)f2bf(v1.w*inv);
  *(bf16x8*)(dst + lane * 8) = o;
}

// ---- stage one 16KB K-tile unit (256 rows x 32 cols bf16), linear LDS ----
// Per wave: 2 x global_load_lds(16B). LDS dest wave-uniform + lane*16.
__device__ __forceinline__ void stage_tile(const unsigned short* __restrict__ g,
                                           unsigned short* lds, int grow_base,
                                           int kt, int w, int l) {
  #pragma unroll
  for (int i = 0; i < 2; ++i) {
    const unsigned short* src = g + (size_t)(grow_base + i*128 + w*16 + (l>>2)) * KD
                                  + kt*BK + (l&3)*8;
    unsigned short* dst = lds + i*4096 + w*512;  // wave-uniform base
    __builtin_amdgcn_global_load_lds(
        (const __attribute__((address_space(1))) void*)src,
        (__attribute__((address_space(3))) void*)dst, 16, 0, 0);
  }
}

// ---- GEMM: out[q][s] = dot(q_bf[q], s_bf[s])  (inputs pre-normalized) ----
// 256x256 tile, BK=32, tri-buffered LDS, counted vmcnt(4), 2 phases/K-tile,
// 16 MFMA/phase with setprio. A=support (D rows) -> dwordx4 epilogue stores.
__global__ __launch_bounds__(512, 1) void gemm_kernel(
    const unsigned short* __restrict__ S,   // [NSUPP][KD] normalized bf16
    const unsigned short* __restrict__ Q,   // [NQRY][KD]  normalized bf16
    float* __restrict__ out) {              // [NQRY][NSUP]
  __shared__ __attribute__((aligned(16))) unsigned short As[3][256][BK];
  __shared__ __attribute__((aligned(16))) unsigned short Bs[3][256][BK];

  const int tid = threadIdx.x;
  const int w = tid >> 6, l = tid & 63;
  const int wm = w >> 2, wn = w & 3;       // wave -> (support half, query quarter)
  const int rof = l & 15, hi = l >> 4;

  // XCD swizzle: 1568 % 8 == 0 -> bijective; each XCD owns one query tile.
  int bid = blockIdx.y * 196 + blockIdx.x;
  bid = (bid & 7) * 196 + (bid >> 3);
  const int ts = (bid % 196) * 256;        // support tile base (padded domain)
  const int tq = (bid / 196) * 256;        // query tile base

  f32x4 acc[8][4] = {};

  // prologue: stage tiles 0 and 1
  stage_tile(S, &As[0][0][0], ts, 0, w, l);
  stage_tile(Q, &Bs[0][0][0], tq, 0, w, l);
  stage_tile(S, &As[1][0][0], ts, 1, w, l);
  stage_tile(Q, &Bs[1][0][0], tq, 1, w, l);
  asm volatile("s_waitcnt vmcnt(4)" ::: "memory");   // tile 0 landed
  __builtin_amdgcn_s_barrier();
  asm volatile("" ::: "memory");

  #pragma unroll
  for (int t = 0; t < NKT; ++t) {
    const int slot  = t % 3;
    const int nslot = (t + 2) % 3;         // never == slot(t) or slot(t+1)
    const int nkt   = (t + 2) & 15;        // t>=14 wrap: dummy stage, keeps vmcnt uniform

    // ---- phase A: read a[0..3] + b[0..3], stage next A-unit, 16 MFMA ----
    bf16x8 a[4], b[4];
    #pragma unroll
    for (int i = 0; i < 4; ++i)
      a[i] = *(const bf16x8*)&As[slot][wm*128 + i*16 + rof][hi*8];
    #pragma unroll
    for (int i = 0; i < 4; ++i)
      b[i] = *(const bf16x8*)&Bs[slot][wn*64 + i*16 + rof][hi*8];
    stage_tile(S, &As[nslot][0][0], ts, nkt, w, l);
    __builtin_amdgcn_s_barrier();
    asm volatile("" ::: "memory");
    __builtin_amdgcn_s_setprio(1);
    #pragma unroll
    for (int mi = 0; mi < 4; ++mi)
      #pragma unroll
      for (int ni = 0; ni < 4; ++ni)
        acc[mi][ni] = __builtin_amdgcn_mfma_f32_16x16x32_bf16(a[mi], b[ni], acc[mi][ni], 0, 0, 0);
    __builtin_amdgcn_s_setprio(0);

    // ---- phase B: read a2[0..3], stage next B-unit, 16 MFMA ----
    bf16x8 a2[4];
    #pragma unroll
    for (int i = 0; i < 4; ++i)
      a2[i] = *(const bf16x8*)&As[slot][wm*128 + 64 + i*16 + rof][hi*8];
    stage_tile(Q, &Bs[nslot][0][0], tq, nkt, w, l);
    __builtin_amdgcn_s_barrier();
    asm volatile("" ::: "memory");
    __builtin_amdgcn_s_setprio(1);
    #pragma unroll
    for (int mi = 0; mi < 4; ++mi)
      #pragma unroll
      for (int ni = 0; ni < 4; ++ni)
        acc[mi+4][ni] = __builtin_amdgcn_mfma_f32_16x16x32_bf16(a2[mi], b[ni], acc[mi+4][ni], 0, 0, 0);
    __builtin_amdgcn_s_setprio(0);

    // tile-end: tile t+1's 4 loads must be landed; tile t+2's 4 may fly on
    asm volatile("s_waitcnt vmcnt(4)" ::: "memory");
    __builtin_amdgcn_s_barrier();
    asm volatile("" ::: "memory");
  }

  // ---- epilogue: D row=(l>>4)*4+r (support, contiguous), col=l&15 (query) ----
  #pragma unroll
  for (int mi = 0; mi < 8; ++mi) {
    const int s = ts + wm*128 + mi*16 + hi*4;   // 4 consecutive supports
    if (s < NSUP) {                              // s%4==0, NSUP%4==0 -> all-or-none
      #pragma unroll
      for (int ni = 0; ni < 4; ++ni) {
        const int q = tq + wn*64 + ni*16 + rof;
        *(f32x4*)(out + (size_t)q * NSUP + s) = acc[mi][ni];   // dwordx4
      }
    }
  }
}

extern "C" void kernel_launch(void* const* d_in, const int* in_sizes, int n_in,
                              void* d_out, int out_size, void* d_ws, size_t ws_size,
                              hipStream_t stream) {
  const float* sup = (const float*)d_in[0];   // [50000][512] f32
  const float* qry = (const float*)d_in[1];   // [2048][512] f32
  float* out = (float*)d_out;                 // [2048][50000] f32

  char* ws = (char*)d_ws;
  unsigned short* s_bf = (unsigned short*)(ws);
  unsigned short* q_bf = (unsigned short*)(ws + (size_t)NSUPP * KD * 2);
  // ws use: 50176*512*2 + 2048*512*2 = 53.5 MB

  prep_kernel<<<(NSUPP + NQRY) / 4, 256, 0, stream>>>(sup, qry, s_bf, q_bf);

  dim3 grid(196, 8);   // support tiles x query tiles
  gemm_kernel<<<grid, 512, 0, stream>>>(s_bf, q_bf, out);
}

// Round 4
// 235.750 us; speedup vs baseline: 1.0100x; 1.0100x over previous
//
#include <hip/hip_runtime.h>
#include <stdint.h>

#define NSUP   50000
#define NSUPP  50176      // padded to multiple of 256
#define NQRY   2048
#define KD     512
#define BK     32
#define NKT    16         // KD / BK

typedef __attribute__((ext_vector_type(8))) short bf16x8;
typedef __attribute__((ext_vector_type(4))) float f32x4;

__device__ __forceinline__ unsigned short f2bf(float f) {
  unsigned int u = __float_as_uint(f);
  u += 0x7FFFu + ((u >> 16) & 1u);   // round-to-nearest-even
  return (unsigned short)(u >> 16);
}

// ---- prep: fused norm + normalize + f32->bf16 (+ zero pad rows) ----
__global__ __launch_bounds__(256) void prep_kernel(
    const float* __restrict__ sup, const float* __restrict__ qry,
    unsigned short* __restrict__ s_bf, unsigned short* __restrict__ q_bf) {
  const int row  = blockIdx.x * 4 + (threadIdx.x >> 6);
  const int lane = threadIdx.x & 63;

  const float* src = nullptr;
  unsigned short* dst;
  if (row < NSUPP) {
    dst = s_bf + (size_t)row * KD;
    if (row < NSUP) src = sup + (size_t)row * KD;
  } else {
    const int r = row - NSUPP;
    dst = q_bf + (size_t)r * KD;
    src = qry + (size_t)r * KD;
  }

  if (src == nullptr) {           // zero pad row
    bf16x8 z = {};
    *(bf16x8*)(dst + lane * 8) = z;
    return;
  }

  const float4 v0 = ((const float4*)src)[lane * 2 + 0];
  const float4 v1 = ((const float4*)src)[lane * 2 + 1];
  float ss = v0.x*v0.x + v0.y*v0.y + v0.z*v0.z + v0.w*v0.w
           + v1.x*v1.x + v1.y*v1.y + v1.z*v1.z + v1.w*v1.w;
  #pragma unroll
  for (int off = 32; off > 0; off >>= 1) ss += __shfl_xor(ss, off);
  const float inv = rsqrtf(fmaxf(ss, 1e-30f));

  bf16x8 o;
  o[0]=(short)f2bf(v0.x*inv); o[1]=(short)f2bf(v0.y*inv);
  o[2]=(short)f2bf(v0.z*inv); o[3]=(short)f2bf(v0.w*inv);
  o[4]=(short)f2bf(v1.x*inv); o[5]=(short)f2bf(v1.y*inv);
  o[6]=(short)f2bf(v1.z*inv); o[7]=(short)f2bf(v1.w*inv);
  *(bf16x8*)(dst + lane * 8) = o;
}

// ---- stage one 16KB K-tile unit (256 rows x 32 cols bf16) ----
// Linear LDS dest (global_load_lds requirement); bank-swizzle applied by
// permuting the GLOBAL source chunk (rule 21): LDS granule [row][c] holds
// global chunk c ^ ((row>>1)&3). Per-wave: 2 x global_load_lds(16B).
__device__ __forceinline__ void stage_tile(const unsigned short* __restrict__ g,
                                           unsigned short* lds, int grow_base,
                                           int kt, int w, int l) {
  const int chunk = (l & 3) ^ ((l >> 3) & 3);   // inverse-swizzled source chunk
  #pragma unroll
  for (int i = 0; i < 2; ++i) {
    const unsigned short* src = g + (size_t)(grow_base + i*128 + w*16 + (l>>2)) * KD
                                  + kt*BK + chunk*8;
    unsigned short* dst = lds + i*4096 + w*512;  // wave-uniform base (+lane*16B)
    __builtin_amdgcn_global_load_lds(
        (const __attribute__((address_space(1))) void*)src,
        (__attribute__((address_space(3))) void*)dst, 16, 0, 0);
  }
}

// swizzled fragment-read element offset for row R, k-granule hi (0..3):
// bank = 16*(R&1) + 4*(hi^((R>>1)&3)) -> 2-way over 16 lanes = conflict-free
#define SWZ_OFF(R, hi) (((hi) ^ (((R) >> 1) & 3)) * 8)

// ---- GEMM: out[q][s] = dot(q_bf[q], s_bf[s])  (inputs pre-normalized) ----
__global__ __launch_bounds__(512, 1) void gemm_kernel(
    const unsigned short* __restrict__ S,   // [NSUPP][KD] normalized bf16
    const unsigned short* __restrict__ Q,   // [NQRY][KD]  normalized bf16
    float* __restrict__ out) {              // [NQRY][NSUP]
  __shared__ __attribute__((aligned(16))) unsigned short As[3][256][BK];
  __shared__ __attribute__((aligned(16))) unsigned short Bs[3][256][BK];

  const int tid = threadIdx.x;
  const int w = tid >> 6, l = tid & 63;
  const int wm = w >> 2, wn = w & 3;
  const int rof = l & 15, hi = l >> 4;

  // XCD swizzle: 1568 % 8 == 0 -> bijective; each XCD owns one query tile.
  int bid = blockIdx.y * 196 + blockIdx.x;
  bid = (bid & 7) * 196 + (bid >> 3);
  const int ts = (bid % 196) * 256;        // support tile base (padded domain)
  const int tq = (bid / 196) * 256;        // query tile base

  f32x4 acc[8][4] = {};

  // prologue: stage tiles 0 and 1
  stage_tile(S, &As[0][0][0], ts, 0, w, l);
  stage_tile(Q, &Bs[0][0][0], tq, 0, w, l);
  stage_tile(S, &As[1][0][0], ts, 1, w, l);
  stage_tile(Q, &Bs[1][0][0], tq, 1, w, l);
  asm volatile("s_waitcnt vmcnt(4)" ::: "memory");   // tile 0 landed
  __builtin_amdgcn_s_barrier();
  asm volatile("" ::: "memory");

  #pragma unroll
  for (int t = 0; t < NKT; ++t) {
    const int slot  = t % 3;
    const int nslot = (t + 2) % 3;         // never == slot(t) or slot(t+1)
    const int nkt   = (t + 2) & 15;        // wrap at t>=14: dummy stage keeps vmcnt uniform

    // ---- phase A: read a[0..3]+b[0..3] (swizzled), stage next A, 16 MFMA ----
    bf16x8 a[4], b[4];
    #pragma unroll
    for (int i = 0; i < 4; ++i) {
      const int R = wm*128 + i*16 + rof;
      a[i] = *(const bf16x8*)&As[slot][R][SWZ_OFF(R, hi)];
    }
    #pragma unroll
    for (int i = 0; i < 4; ++i) {
      const int R = wn*64 + i*16 + rof;
      b[i] = *(const bf16x8*)&Bs[slot][R][SWZ_OFF(R, hi)];
    }
    stage_tile(S, &As[nslot][0][0], ts, nkt, w, l);
    __builtin_amdgcn_s_barrier();
    asm volatile("" ::: "memory");
    __builtin_amdgcn_s_setprio(1);
    #pragma unroll
    for (int mi = 0; mi < 4; ++mi)
      #pragma unroll
      for (int ni = 0; ni < 4; ++ni)
        acc[mi][ni] = __builtin_amdgcn_mfma_f32_16x16x32_bf16(a[mi], b[ni], acc[mi][ni], 0, 0, 0);
    __builtin_amdgcn_s_setprio(0);

    // ---- phase B: read a2[0..3] (swizzled), stage next B, 16 MFMA ----
    bf16x8 a2[4];
    #pragma unroll
    for (int i = 0; i < 4; ++i) {
      const int R = wm*128 + 64 + i*16 + rof;
      a2[i] = *(const bf16x8*)&As[slot][R][SWZ_OFF(R, hi)];
    }
    stage_tile(Q, &Bs[nslot][0][0], tq, nkt, w, l);
    __builtin_amdgcn_s_barrier();
    asm volatile("" ::: "memory");
    __builtin_amdgcn_s_setprio(1);
    #pragma unroll
    for (int mi = 0; mi < 4; ++mi)
      #pragma unroll
      for (int ni = 0; ni < 4; ++ni)
        acc[mi+4][ni] = __builtin_amdgcn_mfma_f32_16x16x32_bf16(a2[mi], b[ni], acc[mi+4][ni], 0, 0, 0);
    __builtin_amdgcn_s_setprio(0);

    // tile-end: t+1's 4 loads must be landed; t+2's 4 may stay in flight
    asm volatile("s_waitcnt vmcnt(4)" ::: "memory");
    __builtin_amdgcn_s_barrier();
    asm volatile("" ::: "memory");
  }

  // ---- epilogue: D row=(l>>4)*4+r (support, contiguous), col=l&15 (query) ----
  #pragma unroll
  for (int mi = 0; mi < 8; ++mi) {
    const int s = ts + wm*128 + mi*16 + hi*4;   // 4 consecutive supports
    if (s < NSUP) {                              // s%4==0, NSUP%4==0 -> all-or-none
      #pragma unroll
      for (int ni = 0; ni < 4; ++ni) {
        const int q = tq + wn*64 + ni*16 + rof;
        *(f32x4*)(out + (size_t)q * NSUP + s) = acc[mi][ni];   // dwordx4
      }
    }
  }
}

extern "C" void kernel_launch(void* const* d_in, const int* in_sizes, int n_in,
                              void* d_out, int out_size, void* d_ws, size_t ws_size,
                              hipStream_t stream) {
  const float* sup = (const float*)d_in[0];   // [50000][512] f32
  const float* qry = (const float*)d_in[1];   // [2048][512] f32
  float* out = (float*)d_out;                 // [2048][50000] f32

  char* ws = (char*)d_ws;
  unsigned short* s_bf = (unsigned short*)(ws);
  unsigned short* q_bf = (unsigned short*)(ws + (size_t)NSUPP * KD * 2);
  // ws use: 50176*512*2 + 2048*512*2 = 53.5 MB

  prep_kernel<<<(NSUPP + NQRY) / 4, 256, 0, stream>>>(sup, qry, s_bf, q_bf);

  dim3 grid(196, 8);   // support tiles x query tiles
  gemm_kernel<<<grid, 512, 0, stream>>>(s_bf, q_bf, out);
}